// Round 7
// baseline (368.206 us; speedup 1.0000x reference)
//
#include <hip/hip_runtime.h>
#include <hip/hip_fp16.h>
#include <stdint.h>

// Problem constants: B=4, S=128 -> M=512
#define M_DIM 512
#define K_DIM 4096
#define N_DIM 11008
#define KT (K_DIM / 64)        // 64 k-tiles of BK=64
#define NB_M 8                 // 64-row strips
#define NB_N 172               // 64-col strips
#define NBLK (NB_M * NB_N)     // 1376 two-wave blocks (split-K=2 inside the block)

typedef __attribute__((ext_vector_type(8))) _Float16 half8;
typedef __attribute__((ext_vector_type(4))) float floatx4;
typedef __attribute__((ext_vector_type(4))) int intx4;
typedef __attribute__((ext_vector_type(4))) unsigned int uintx4;

__device__ __forceinline__ unsigned int h2u(__half2 h) {
    union { __half2 h; unsigned int u; } c; c.h = h; return c.u;
}
__device__ __forceinline__ __half2 u2h(unsigned int u) {
    union { unsigned int u; __half2 h; } c; c.u = u; return c.h;
}
union U4H8 { uintx4 u; half8 h; };

// one packed dword (8 codes, pair-interleaved) -> b-operand half8 (R5-proven)
__device__ __forceinline__ half8 dequant8(unsigned int dw, __half2 s2, __half2 z2) {
    const __half2 kb = u2h(0x64006400u);   // (1024, 1024)
    U4H8 r;
    unsigned int p0 = (dw & 0x000F000Fu) | 0x64006400u;
    unsigned int p1 = ((dw >> 4)  & 0x000F000Fu) | 0x64006400u;
    unsigned int p2 = ((dw >> 8)  & 0x000F000Fu) | 0x64006400u;
    unsigned int p3 = ((dw >> 12) & 0x000F000Fu) | 0x64006400u;
    r.u.x = h2u(__hfma2(__hsub2(u2h(p0), kb), s2, z2));
    r.u.y = h2u(__hfma2(__hsub2(u2h(p1), kb), s2, z2));
    r.u.z = h2u(__hfma2(__hsub2(u2h(p2), kb), s2, z2));
    r.u.w = h2u(__hfma2(__hsub2(u2h(p3), kb), s2, z2));
    return r.h;
}

// ---------------------------------------------------------------------------
// Merged prep kernel — EXACT R2/R4 version (proven; do not touch).
// Blocks [0,1024): x fp32 -> f16 fragment-linear xb. Blocks [1024,12032):
// wq int32 -> packed nibbles, tile-major [nb][kt], dword idx = q*128 + r.
// ---------------------------------------------------------------------------
__global__ __launch_bounds__(256) void prep_kernel(
        const float* __restrict__ x,  unsigned int* __restrict__ xb,
        const int*   __restrict__ wq, unsigned int* __restrict__ wpk) {
    int bx = blockIdx.x;
    if (bx < 1024) {
        int id = bx * 256 + threadIdx.x;        // chunk id, 262144 total
        int m  = id >> 9;
        int kc = id & 511;                      // k-octet within row
        const floatx4* src = (const floatx4*)(x + ((size_t)m << 12) + (kc << 3));
        floatx4 f0 = __builtin_nontemporal_load(src);
        floatx4 f1 = __builtin_nontemporal_load(src + 1);
        uintx4 v;
        v.x = h2u(__float22half2_rn(float2{f0.x, f0.y}));
        v.y = h2u(__float22half2_rn(float2{f0.z, f0.w}));
        v.z = h2u(__float22half2_rn(float2{f1.x, f1.y}));
        v.w = h2u(__float22half2_rn(float2{f1.z, f1.w}));
        int tm = m >> 7, r = m & 127, tk = kc >> 3, c = kc & 7;
        int igrp = r >> 4, rlow = r & 15, s01 = c >> 2, q = c & 3;
        int chunk = ((igrp * 2 + s01) << 6) + (q << 4) + rlow;
        size_t dstu = (((size_t)(tm * KT + tk)) << 12) + ((size_t)chunk << 2);
        *((uintx4*)(xb + dstu)) = v;
    } else {
        int id   = (bx - 1024) * 256 + threadIdx.x;
        int tile = id >> 9;                     // 5504 tiles (86 nb x 64 kt)
        int p    = id & 511;
        int nb = tile >> 6, kt = tile & 63;
        int r = p >> 2, q0 = (p & 3) * 2;
        const intx4* src = (const intx4*)(wq + (size_t)(nb * 128 + r) * K_DIM + kt * 64 + q0 * 8);
        intx4 a0 = __builtin_nontemporal_load(src);
        intx4 a1 = __builtin_nontemporal_load(src + 1);
        intx4 a2 = __builtin_nontemporal_load(src + 2);
        intx4 a3 = __builtin_nontemporal_load(src + 3);
        unsigned int u0 =
            (unsigned)a0.x | ((unsigned)a0.z << 4)  | ((unsigned)a1.x << 8)  | ((unsigned)a1.z << 12) |
            ((unsigned)a0.y << 16) | ((unsigned)a0.w << 20) | ((unsigned)a1.y << 24) | ((unsigned)a1.w << 28);
        unsigned int u1 =
            (unsigned)a2.x | ((unsigned)a2.z << 4)  | ((unsigned)a3.x << 8)  | ((unsigned)a3.z << 12) |
            ((unsigned)a2.y << 16) | ((unsigned)a2.w << 20) | ((unsigned)a3.y << 24) | ((unsigned)a3.w << 28);
        size_t base = ((size_t)tile) << 10;
        wpk[base + (q0 << 7) + r]       = u0;
        wpk[base + ((q0 + 1) << 7) + r] = u1;
    }
}

// ---------------------------------------------------------------------------
// GEMM. Two waves per block, split-K=2 inside the block — EXACT R4 structure
// (best: 354.2 us; R5 pair-unroll and R6 4-wave both regressed) with two
// counter-driven fixes from R5's visible gemm dispatch:
//  (1) W prefetch DEPTH 2 (qw/qwn/qwn2): lead ~710 cyc of issue work vs the
//      ~600 cyc L2-miss->L3 latency of the W stream (FETCH 110 MB showed W
//      misses L2 on every XCD). Scale prefetch moved to even-kt: 2-kt lead
//      for the 2.8 MB saz stream (also L2-miss latency).
//  (2) PLAIN stores in the epilogue. R5 measured WRITE_SIZE=148 MB for a
//      22.5 MB output: nontemporal scattered-dword stores defeat L2 write
//      merging of the 4x64 B segments per 256 B row-span -> 6.5x write
//      amplification + read-back FETCH. Plain stores let L2 merge.
// Live VGPR ~167 (R4 ~159 + 8 for qwn2) — inside the 3-waves/SIMD cap.
// ---------------------------------------------------------------------------
__global__ __launch_bounds__(128, 3) void gemm_kernel(
        const unsigned int* __restrict__ xb,    // fragment-linear f16 x
        const unsigned int* __restrict__ wpk,   // packed nibbles, [q][r] tiles
        const float*        __restrict__ saz,   // [K/128, N, 2]
        float*              __restrict__ out)   // [M,N] fp32 (fully written here)
{
    const int bx   = blockIdx.x;
    const int mbp  = bx & 7;                   // 64-row strip 0..7 (== XCD id)
    const int nbp  = bx >> 3;                  // 64-col strip 0..171
    const int lane = threadIdx.x & 63;
    const int wid  = threadIdx.x >> 6;         // split-K half 0/1
    const int q4   = lane >> 4;
    const int lr   = lane & 15;
    const int kt0  = wid * (KT / 2);
    const int kt1  = kt0 + (KT / 2);           // 32 k-tiles per wave

    const int tm    = mbp >> 1;                // xb 128-row tile
    const int igrp0 = (mbp & 1) * 4;           // first 16-row group
    const int nbt   = nbp >> 1;                // wpk 128-col tile
    const int wn    = (nbp & 1) * 64;

    // A fragments: 16 B units; frag (i, s01) at xat[i*128 + s01*64]
    const half8* xat = (const half8*)xb
        + (((size_t)(tm * KT + kt0)) << 10) + (igrp0 << 7) + lane;

    // W: frag (j, s01) at wbase[s01*512 + j*16]; 1024 dwords per k-tile
    const unsigned int* wbase =
        wpk + (((size_t)(nbt * KT + kt0)) << 10) + (q4 << 7) + wn + lr;

    const float2* saz2 = (const float2*)saz;
    const int nrow0 = nbp * 64 + lr;           // n-row for frag j: +j*16
    const float2* sazp = saz2 + (size_t)(kt0 >> 1) * N_DIM + nrow0;

    floatx4 acc[4][4];
    floatx4 zero4 = {0.f, 0.f, 0.f, 0.f};
#pragma unroll
    for (int i = 0; i < 4; ++i)
#pragma unroll
        for (int j = 0; j < 4; ++j)
            acc[i][j] = zero4;

    // prologue: W for kt0 AND kt0+1 (depth-2), A s0-half of kt0, scales grp 0
    unsigned int qw[8], qwn[8], qwn2[8];
#pragma unroll
    for (int f = 0; f < 8; ++f)
        qw[f] = wbase[(f >> 2) * 512 + (f & 3) * 16];
    wbase += 1024;
#pragma unroll
    for (int f = 0; f < 8; ++f)
        qwn[f] = wbase[(f >> 2) * 512 + (f & 3) * 16];

    half8 av0[4], av1[4], av0n[4];
#pragma unroll
    for (int i = 0; i < 4; ++i)
        av0[i] = xat[i * 128];

    float2 sf[4];
#pragma unroll
    for (int t = 0; t < 4; ++t)
        sf[t] = sazp[t * 16];

    __half2 s2[4], z2[4];

    for (int kt = kt0; kt < kt1; ++kt) {
        const bool more1 = (kt + 1 < kt1);
        const bool more2 = (kt + 2 < kt1);

        // scales: convert on even kt (sf loaded 2 kt ago), then immediately
        // issue the NEXT group's raw loads (2-kt lead > L2-miss latency)
        if ((kt & 1) == 0) {
#pragma unroll
            for (int t = 0; t < 4; ++t) {
                s2[t] = __float2half2_rn(sf[t].x);
                z2[t] = __float2half2_rn(fmaf(-8.f, sf[t].x, sf[t].y));
            }
            if (more2) {
                sazp += N_DIM;
#pragma unroll
                for (int t = 0; t < 4; ++t)
                    sf[t] = sazp[t * 16];
            }
        }

        // issue W prefetch for kt+2 (depth-2: ~2 kt of issue work in flight)
        if (more2) {
            wbase += 1024;                      // now at kt+2
#pragma unroll
            for (int f = 0; f < 8; ++f)
                qwn2[f] = wbase[(f >> 2) * 512 + (f & 3) * 16];
        }

        // issue this-kt s1-half A loads (consumed after the s0 MFMA block)
#pragma unroll
        for (int i = 0; i < 4; ++i)
            av1[i] = xat[i * 128 + 64];

        // s01 = 0: dequant + 16 MFMA on av0 (prefetched during prev iter)
#pragma unroll
        for (int j = 0; j < 4; ++j) {
            half8 bv = dequant8(qw[j], s2[j], z2[j]);
#pragma unroll
            for (int i = 0; i < 4; ++i)
                acc[i][j] = __builtin_amdgcn_mfma_f32_16x16x32_f16(
                    av0[i], bv, acc[i][j], 0, 0, 0);
        }

        // issue next-kt s0-half A loads (consumed next iteration)
        if (more1) {
#pragma unroll
            for (int i = 0; i < 4; ++i)
                av0n[i] = xat[1024 + i * 128];
        }

        // s01 = 1: dequant + 16 MFMA on av1 (covered by the s0 block)
#pragma unroll
        for (int j = 0; j < 4; ++j) {
            half8 bv = dequant8(qw[4 + j], s2[j], z2[j]);
#pragma unroll
            for (int i = 0; i < 4; ++i)
                acc[i][j] = __builtin_amdgcn_mfma_f32_16x16x32_f16(
                    av1[i], bv, acc[i][j], 0, 0, 0);
        }

        xat += 1024;
#pragma unroll
        for (int i = 0; i < 4; ++i) av0[i] = av0n[i];
#pragma unroll
        for (int f = 0; f < 8; ++f) qw[f] = qwn[f];
        if (more2) {
#pragma unroll
            for (int f = 0; f < 8; ++f) qwn[f] = qwn2[f];
        }
    }

    // ---------------------------------------------------------------------
    // Epilogue: C/D layout col = lane&15 (n), row = q4*4 + reg (m).
    // Cross-wave reduction through padded LDS; PLAIN stores (no nt): R5
    // measured nt scattered-dword stores at 6.5x write amplification —
    // plain stores let L2 merge the 64 B segments into full lines.
    // ---------------------------------------------------------------------
    __shared__ float red[2][32 * 65];
    float* don = red[wid];
    const int id0 = wid ? 0 : 2;               // donated i-range
#pragma unroll
    for (int ii = 0; ii < 2; ++ii) {
        const int i = id0 + ii;
#pragma unroll
        for (int j = 0; j < 4; ++j)
#pragma unroll
            for (int rr = 0; rr < 4; ++rr) {
                const int rl = (i * 16 + q4 * 4 + rr) & 31;
                don[rl * 65 + j * 16 + lr] = acc[i][j][rr];
            }
    }
    __syncthreads();
    const float* oth = red[wid ^ 1];
    const int ik0 = wid ? 2 : 0;               // kept i-range
    const int n0 = nbp * 64 + lr;
#pragma unroll
    for (int ii = 0; ii < 2; ++ii) {
        const int i = ik0 + ii;
#pragma unroll
        for (int j = 0; j < 4; ++j) {
            float* o = out + (size_t)(mbp * 64 + i * 16 + q4 * 4) * N_DIM + (n0 + j * 16);
#pragma unroll
            for (int rr = 0; rr < 4; ++rr) {
                const int rl = (i * 16 + q4 * 4 + rr) & 31;
                o[(size_t)rr * N_DIM] = acc[i][j][rr] + oth[rl * 65 + j * 16 + lr];
            }
        }
    }
}

extern "C" void kernel_launch(void* const* d_in, const int* in_sizes, int n_in,
                              void* d_out, int out_size, void* d_ws, size_t ws_size,
                              hipStream_t stream) {
    const float* x   = (const float*)d_in[0];
    const int*   wq  = (const int*)d_in[1];
    const float* saz = (const float*)d_in[2];

    // ws layout: [wpk: 22,544,384 B packed weights][xb: 4 MB f16 x]
    unsigned int* wpk = (unsigned int*)d_ws;
    unsigned int* xb  = (unsigned int*)((char*)d_ws + 22544384);

    // No output memset: gemm writes every element exactly once (no atomics).
    prep_kernel<<<dim3(12032), dim3(256), 0, stream>>>(x, xb, wq, wpk);
    gemm_kernel<<<dim3(NBLK), dim3(128), 0, stream>>>(xb, wpk, saz, (float*)d_out);
}

// Round 8
// 356.395 us; speedup vs baseline: 1.0331x; 1.0331x over previous
//
#include <hip/hip_runtime.h>
#include <hip/hip_fp16.h>
#include <stdint.h>

// Problem constants: B=4, S=128 -> M=512
#define M_DIM 512
#define K_DIM 4096
#define N_DIM 11008
#define KT (K_DIM / 64)        // 64 k-tiles of BK=64
#define NB_M 8                 // 64-row strips
#define NB_N 172               // 64-col strips
#define NBLK (NB_M * NB_N)     // 1376 two-wave blocks (split-K=2 inside the block)

typedef __attribute__((ext_vector_type(8))) _Float16 half8;
typedef __attribute__((ext_vector_type(4))) float floatx4;
typedef __attribute__((ext_vector_type(4))) int intx4;
typedef __attribute__((ext_vector_type(4))) unsigned int uintx4;

__device__ __forceinline__ unsigned int h2u(__half2 h) {
    union { __half2 h; unsigned int u; } c; c.h = h; return c.u;
}
__device__ __forceinline__ __half2 u2h(unsigned int u) {
    union { unsigned int u; __half2 h; } c; c.u = u; return c.h;
}
union U4H8 { uintx4 u; half8 h; };

// one packed dword (8 codes, pair-interleaved) -> b-operand half8 (R5-proven)
__device__ __forceinline__ half8 dequant8(unsigned int dw, __half2 s2, __half2 z2) {
    const __half2 kb = u2h(0x64006400u);   // (1024, 1024)
    U4H8 r;
    unsigned int p0 = (dw & 0x000F000Fu) | 0x64006400u;
    unsigned int p1 = ((dw >> 4)  & 0x000F000Fu) | 0x64006400u;
    unsigned int p2 = ((dw >> 8)  & 0x000F000Fu) | 0x64006400u;
    unsigned int p3 = ((dw >> 12) & 0x000F000Fu) | 0x64006400u;
    r.u.x = h2u(__hfma2(__hsub2(u2h(p0), kb), s2, z2));
    r.u.y = h2u(__hfma2(__hsub2(u2h(p1), kb), s2, z2));
    r.u.z = h2u(__hfma2(__hsub2(u2h(p2), kb), s2, z2));
    r.u.w = h2u(__hfma2(__hsub2(u2h(p3), kb), s2, z2));
    return r.h;
}

// ---------------------------------------------------------------------------
// Merged prep kernel. LOAD side EXACTLY as R2/R4 (proven; R3 showed breaking
// the 4-lanes-per-line wq read pattern costs 31 us on the 180 MB stream).
// NEW: wpk tile layout is LANE-LINEAR for the gemm:
//   idx' = h*512 + (q4*16 + lr)*8 + s01*4 + j
// (h = n-half, lane = q4*16+lr, q = s01*4+q4 k-octet, row r = h*64+j*16+lr)
// so each gemm lane's 8 dwords per k-tile are CONTIGUOUS 32 B -> the wave
// loads W as 2x global_load_dwordx4 (2 KB dense) instead of 8 scattered
// dwords touching 32 half-line segments. Prep-side cost: the two stores per
// thread scatter within the hot 4 KB tile region (L2-merged).
// Identity: u1 (q=q0+1) lands at u0's index + 128 dwords.
// ---------------------------------------------------------------------------
__global__ __launch_bounds__(256) void prep_kernel(
        const float* __restrict__ x,  unsigned int* __restrict__ xb,
        const int*   __restrict__ wq, unsigned int* __restrict__ wpk) {
    int bx = blockIdx.x;
    if (bx < 1024) {
        int id = bx * 256 + threadIdx.x;        // chunk id, 262144 total
        int m  = id >> 9;
        int kc = id & 511;                      // k-octet within row
        const floatx4* src = (const floatx4*)(x + ((size_t)m << 12) + (kc << 3));
        floatx4 f0 = __builtin_nontemporal_load(src);
        floatx4 f1 = __builtin_nontemporal_load(src + 1);
        uintx4 v;
        v.x = h2u(__float22half2_rn(float2{f0.x, f0.y}));
        v.y = h2u(__float22half2_rn(float2{f0.z, f0.w}));
        v.z = h2u(__float22half2_rn(float2{f1.x, f1.y}));
        v.w = h2u(__float22half2_rn(float2{f1.z, f1.w}));
        int tm = m >> 7, r = m & 127, tk = kc >> 3, c = kc & 7;
        int igrp = r >> 4, rlow = r & 15, s01 = c >> 2, q = c & 3;
        int chunk = ((igrp * 2 + s01) << 6) + (q << 4) + rlow;
        size_t dstu = (((size_t)(tm * KT + tk)) << 12) + ((size_t)chunk << 2);
        *((uintx4*)(xb + dstu)) = v;
    } else {
        int id   = (bx - 1024) * 256 + threadIdx.x;
        int tile = id >> 9;                     // 5504 tiles (86 nb x 64 kt)
        int p    = id & 511;
        int nb = tile >> 6, kt = tile & 63;
        int r = p >> 2, q0 = (p & 3) * 2;       // r = n-row, q0 = even k-octet
        const intx4* src = (const intx4*)(wq + (size_t)(nb * 128 + r) * K_DIM + kt * 64 + q0 * 8);
        intx4 a0 = __builtin_nontemporal_load(src);
        intx4 a1 = __builtin_nontemporal_load(src + 1);
        intx4 a2 = __builtin_nontemporal_load(src + 2);
        intx4 a3 = __builtin_nontemporal_load(src + 3);
        unsigned int u0 =
            (unsigned)a0.x | ((unsigned)a0.z << 4)  | ((unsigned)a1.x << 8)  | ((unsigned)a1.z << 12) |
            ((unsigned)a0.y << 16) | ((unsigned)a0.w << 20) | ((unsigned)a1.y << 24) | ((unsigned)a1.w << 28);
        unsigned int u1 =
            (unsigned)a2.x | ((unsigned)a2.z << 4)  | ((unsigned)a3.x << 8)  | ((unsigned)a3.z << 12) |
            ((unsigned)a2.y << 16) | ((unsigned)a2.w << 20) | ((unsigned)a3.y << 24) | ((unsigned)a3.w << 28);
        // lane-linear layout: idx' = h*512 + ((q&3)*16 + (r&15))*8 + (q>>2)*4 + j
        int hh = r >> 6, lr2 = r & 15, j2 = (r & 63) >> 4;
        size_t i0 = (((size_t)tile) << 10) + (hh << 9)
                  + (((q0 & 3) << 4) + lr2) * 8 + ((q0 >> 2) << 2) + j2;
        wpk[i0]       = u0;                     // q = q0
        wpk[i0 + 128] = u1;                     // q = q0+1: (q&3)+1 -> +16*8
    }
}

// ---------------------------------------------------------------------------
// GEMM. Two waves per block, split-K=2 inside the block — EXACT R4 structure
// (best: 354.2 us; R5/R6/R7 variants all regressed) with ONE delta:
// W loads are now 2x dwordx4 per k-tile (lane-linear wpk layout) instead of
// 8 scattered dwords — 4x fewer W load instructions, ~2x fewer L1/L2 line
// transactions, full 128 B line utilization on the hottest stream.
// Depth-1 W prefetch (qw/qwn), A s0/s1 split, odd-kt scale prefetch (R4).
// Plain epilogue stores (R7 counter: nt stores gave 148 MB WRITE vs 126).
// ---------------------------------------------------------------------------
__global__ __launch_bounds__(128, 3) void gemm_kernel(
        const unsigned int* __restrict__ xb,    // fragment-linear f16 x
        const unsigned int* __restrict__ wpk,   // packed nibbles, lane-linear tiles
        const float*        __restrict__ saz,   // [K/128, N, 2]
        float*              __restrict__ out)   // [M,N] fp32 (fully written here)
{
    const int bx   = blockIdx.x;
    const int mbp  = bx & 7;                   // 64-row strip 0..7 (== XCD id)
    const int nbp  = bx >> 3;                  // 64-col strip 0..171
    const int lane = threadIdx.x & 63;
    const int wid  = threadIdx.x >> 6;         // split-K half 0/1
    const int q4   = lane >> 4;
    const int lr   = lane & 15;
    const int kt0  = wid * (KT / 2);
    const int kt1  = kt0 + (KT / 2);           // 32 k-tiles per wave

    const int tm    = mbp >> 1;                // xb 128-row tile
    const int igrp0 = (mbp & 1) * 4;           // first 16-row group
    const int nbt   = nbp >> 1;                // wpk 128-col tile
    const int hh    = nbp & 1;                 // n-half within the 128-col tile

    // A fragments: 16 B units; frag (i, s01) at xat[i*128 + s01*64]
    const half8* xat = (const half8*)xb
        + (((size_t)(tm * KT + kt0)) << 10) + (igrp0 << 7) + lane;

    // W: lane-linear — this lane's 8 dwords/kt at wb4[0..1] (2x uintx4);
    // advance 256 uintx4 (1024 dwords) per k-tile
    const uintx4* wb4 = (const uintx4*)
        (wpk + (((size_t)(nbt * KT + kt0)) << 10) + (hh << 9)) + lane * 2;

    const float2* saz2 = (const float2*)saz;
    const int nrow0 = nbp * 64 + lr;           // n-row for frag j: +j*16
    const float2* sazp = saz2 + (size_t)(kt0 >> 1) * N_DIM + nrow0;

    floatx4 acc[4][4];
    floatx4 zero4 = {0.f, 0.f, 0.f, 0.f};
#pragma unroll
    for (int i = 0; i < 4; ++i)
#pragma unroll
        for (int j = 0; j < 4; ++j)
            acc[i][j] = zero4;

    // prologue: W (2x dwordx4) + A s0-half for kt0, raw scales for group 0
    uintx4 qwa, qwb, qwna, qwnb;
    qwa = wb4[0];
    qwb = wb4[1];

    half8 av0[4], av1[4], av0n[4];
#pragma unroll
    for (int i = 0; i < 4; ++i)
        av0[i] = xat[i * 128];

    float2 sf[4];
#pragma unroll
    for (int t = 0; t < 4; ++t)
        sf[t] = sazp[t * 16];

    __half2 s2[4], z2[4];

    for (int kt = kt0; kt < kt1; ++kt) {
        const bool more = (kt + 1 < kt1);

        // scales: convert on even kt (sf prefetched during the prior odd kt)
        if ((kt & 1) == 0) {
#pragma unroll
            for (int t = 0; t < 4; ++t) {
                s2[t] = __float2half2_rn(sf[t].x);
                z2[t] = __float2half2_rn(fmaf(-8.f, sf[t].x, sf[t].y));
            }
        } else if (more) {
            sazp += N_DIM;
#pragma unroll
            for (int t = 0; t < 4; ++t)
                sf[t] = sazp[t * 16];
        }

        // prefetch next k-tile's W (2 instructions, in flight during MFMA)
        if (more) {
            qwna = wb4[256];
            qwnb = wb4[257];
        }

        // issue this-kt s1-half A loads (consumed after the s0 MFMA block)
#pragma unroll
        for (int i = 0; i < 4; ++i)
            av1[i] = xat[i * 128 + 64];

        // s01 = 0: dequant + 16 MFMA on av0 (prefetched during prev iter)
#pragma unroll
        for (int j = 0; j < 4; ++j) {
            half8 bv = dequant8(qwa[j], s2[j], z2[j]);
#pragma unroll
            for (int i = 0; i < 4; ++i)
                acc[i][j] = __builtin_amdgcn_mfma_f32_16x16x32_f16(
                    av0[i], bv, acc[i][j], 0, 0, 0);
        }

        // issue next-kt s0-half A loads (consumed next iteration)
        if (more) {
#pragma unroll
            for (int i = 0; i < 4; ++i)
                av0n[i] = xat[1024 + i * 128];
        }

        // s01 = 1: dequant + 16 MFMA on av1 (covered by the s0 block)
#pragma unroll
        for (int j = 0; j < 4; ++j) {
            half8 bv = dequant8(qwb[j], s2[j], z2[j]);
#pragma unroll
            for (int i = 0; i < 4; ++i)
                acc[i][j] = __builtin_amdgcn_mfma_f32_16x16x32_f16(
                    av1[i], bv, acc[i][j], 0, 0, 0);
        }

        xat += 1024;
        wb4 += 256;
#pragma unroll
        for (int i = 0; i < 4; ++i) av0[i] = av0n[i];
        qwa = qwna;
        qwb = qwnb;
    }

    // ---------------------------------------------------------------------
    // Epilogue: C/D layout col = lane&15 (n), row = q4*4 + reg (m).
    // Cross-wave reduction through padded LDS; plain stores, no atomics.
    // ---------------------------------------------------------------------
    __shared__ float red[2][32 * 65];
    float* don = red[wid];
    const int id0 = wid ? 0 : 2;               // donated i-range
#pragma unroll
    for (int ii = 0; ii < 2; ++ii) {
        const int i = id0 + ii;
#pragma unroll
        for (int j = 0; j < 4; ++j)
#pragma unroll
            for (int rr = 0; rr < 4; ++rr) {
                const int rl = (i * 16 + q4 * 4 + rr) & 31;
                don[rl * 65 + j * 16 + lr] = acc[i][j][rr];
            }
    }
    __syncthreads();
    const float* oth = red[wid ^ 1];
    const int ik0 = wid ? 2 : 0;               // kept i-range
    const int n0 = nbp * 64 + lr;
#pragma unroll
    for (int ii = 0; ii < 2; ++ii) {
        const int i = ik0 + ii;
#pragma unroll
        for (int j = 0; j < 4; ++j) {
            float* o = out + (size_t)(mbp * 64 + i * 16 + q4 * 4) * N_DIM + (n0 + j * 16);
#pragma unroll
            for (int rr = 0; rr < 4; ++rr) {
                const int rl = (i * 16 + q4 * 4 + rr) & 31;
                o[(size_t)rr * N_DIM] = acc[i][j][rr] + oth[rl * 65 + j * 16 + lr];
            }
        }
    }
}

extern "C" void kernel_launch(void* const* d_in, const int* in_sizes, int n_in,
                              void* d_out, int out_size, void* d_ws, size_t ws_size,
                              hipStream_t stream) {
    const float* x   = (const float*)d_in[0];
    const int*   wq  = (const int*)d_in[1];
    const float* saz = (const float*)d_in[2];

    // ws layout: [wpk: 22,544,384 B packed weights][xb: 4 MB f16 x]
    unsigned int* wpk = (unsigned int*)d_ws;
    unsigned int* xb  = (unsigned int*)((char*)d_ws + 22544384);

    // No output memset: gemm writes every element exactly once (no atomics).
    prep_kernel<<<dim3(12032), dim3(256), 0, stream>>>(x, xb, wq, wpk);
    gemm_kernel<<<dim3(NBLK), dim3(128), 0, stream>>>(xb, wpk, saz, (float*)d_out);
}